// Round 10
// baseline (92.526 us; speedup 1.0000x reference)
//
#include <hip/hip_runtime.h>
#include <math.h>

#define N_T 32768
#define L 65536
#define BATCH 64
#define NPAIR 32
#define NEV 8
#define NROOM 16
#define ROWP 258
#define TP 17
#define TWO_PI 6.2831853071795864769f
#define INV_L (1.0f / 65536.0f)
// tiled layouts
#define TILE_C 4096                  // float2 per C tile: [256 p][16 c]
#define CB (16 * TILE_C)             // float2 per batch in C
#define DTILE (128 * 16)             // floats per dry/K/wout tile: [128 n2][16 c]
#define DB (16 * DTILE)              // floats per batch

__device__ __forceinline__ float2 cmul(float2 a, float2 b) {
    return make_float2(a.x * b.x - a.y * b.y, a.x * b.y + a.y * b.x);
}
// base-4 digit reversal of an 8-bit index (involution)
__device__ __forceinline__ int dr4(int p) {
    return ((p & 3) << 6) | ((p & 12) << 2) | ((p & 48) >> 2) | ((p & 192) >> 6);
}

// register radix-4 DIF butterfly (fwd)
__device__ __forceinline__ void bf4f(float2& a, float2& b, float2& c, float2& d,
                                     const float2* tw, int f, int q) {
    float2 t0 = make_float2(a.x + c.x, a.y + c.y);
    float2 t1 = make_float2(a.x - c.x, a.y - c.y);
    float2 t2 = make_float2(b.x + d.x, b.y + d.y);
    float2 u  = make_float2(b.x - d.x, b.y - d.y);
    float2 t3 = make_float2(u.y, -u.x);            // -i*u
    a = make_float2(t0.x + t2.x, t0.y + t2.y);
    b = cmul(make_float2(t1.x + t3.x, t1.y + t3.y), tw[f * q]);
    c = cmul(make_float2(t0.x - t2.x, t0.y - t2.y), tw[2 * f * q]);
    d = cmul(make_float2(t1.x - t3.x, t1.y - t3.y), tw[3 * f * q]);
}
// register radix-4 DIT butterfly (inv): exact inverse of bf4f
__device__ __forceinline__ void bf4i(float2& a, float2& b, float2& c, float2& d,
                                     const float2* tw, int f, int q) {
    float2 w1 = tw[f * q], w2 = tw[2 * f * q], w3 = tw[3 * f * q];
    float2 y0 = a;
    float2 y1 = cmul(b, make_float2(w1.x, -w1.y));
    float2 y2 = cmul(c, make_float2(w2.x, -w2.y));
    float2 y3 = cmul(d, make_float2(w3.x, -w3.y));
    float2 t0 = make_float2(y0.x + y2.x, y0.y + y2.y);
    float2 t2 = make_float2(y0.x - y2.x, y0.y - y2.y);
    float2 t1 = make_float2(y1.x + y3.x, y1.y + y3.y);
    float2 u  = make_float2(y1.x - y3.x, y1.y - y3.y);
    a = make_float2(t0.x + t1.x, t0.y + t1.y);
    b = make_float2(t2.x - u.y, t2.y + u.x);
    c = make_float2(t0.x - t1.x, t0.y - t1.y);
    d = make_float2(t2.x + u.y, t2.y - u.x);
}
__device__ __forceinline__ void bfly4_fwd(float2* A, int a0, int st, const float2* tw, int f, int q) {
    bf4f(A[a0], A[a0 + st], A[a0 + 2 * st], A[a0 + 3 * st], tw, f, q);
}
__device__ __forceinline__ void bfly4_inv(float2* A, int a0, int st, const float2* tw, int f, int q) {
    bf4i(A[a0], A[a0 + st], A[a0 + 2 * st], A[a0 + 3 * st], tw, f, q);
}

// ---- gating ----
__global__ void k_prep(const float* __restrict__ g, const float* __restrict__ w_room,
                       const float* __restrict__ b_room, const float* __restrict__ w_mix,
                       const float* __restrict__ b_mix,
                       float* __restrict__ wroom, float* __restrict__ mixv) {
    int b = threadIdx.x;
    if (b >= BATCH) return;
    float logits[NROOM];
    for (int r = 0; r < NROOM; r++) logits[r] = b_room[r];
    float acc_mix = b_mix[0];
    for (int d = 0; d < 128; d++) {
        float gv = g[b * 128 + d];
        for (int r = 0; r < NROOM; r++) logits[r] += gv * w_room[d * NROOM + r];
        acc_mix += gv * w_mix[d];
    }
    float m = logits[0];
    for (int r = 1; r < NROOM; r++) m = fmaxf(m, logits[r]);
    float s = 0.f;
    for (int r = 0; r < NROOM; r++) { logits[r] = expf(logits[r] - m); s += logits[r]; }
    float inv = 1.f / s;
    for (int r = 0; r < NROOM; r++) wroom[b * NROOM + r] = logits[r] * inv;
    mixv[b] = 1.f / (1.f + expf(-acc_mix));
}

// ---- dry + K builder: contiguous event reads, tiled writes ----
__global__ void k_dryk(const float* __restrict__ events, const int* __restrict__ indices,
                       const float* __restrict__ rooms, const float* __restrict__ wroom,
                       float* __restrict__ dryT, float* __restrict__ KT) {
    int b = blockIdx.x >> 3;
    int gseg = blockIdx.x & 7;             // t-range [4096*gseg, +4096)
    int t = threadIdx.x;
    const float* eb = events + (size_t)b * NEV * N_T;
    const int* ib = indices + b * NEV;
    const float* wb = wroom + b * NROOM;
    int sh[NEV];
#pragma unroll
    for (int e = 0; e < NEV; e++) sh[e] = ib[e] << 8;
    float wr[NROOM];
#pragma unroll
    for (int r = 0; r < NROOM; r++) wr[r] = wb[r];
    int base = gseg * 4096;
    for (int i = 0; i < 4; i++) {
        int t0 = base + i * 1024 + t * 4;
        float4 d = make_float4(0.f, 0.f, 0.f, 0.f);
#pragma unroll
        for (int e = 0; e < NEV; e++) {
            int n = t0 - sh[e];
            if (n >= 0) {
                float4 v = *(const float4*)(eb + e * N_T + n);
                d.x += v.x; d.y += v.y; d.z += v.z; d.w += v.w;
            }
        }
        float4 k = make_float4(0.f, 0.f, 0.f, 0.f);
#pragma unroll
        for (int r = 0; r < NROOM; r++) {
            float w = wr[r];
            float4 rv = *(const float4*)(rooms + (size_t)r * N_T + t0);
            k.x += w * rv.x; k.y += w * rv.y; k.z += w * rv.z; k.w += w * rv.w;
        }
        int n2 = t0 >> 8, c = t0 & 255;
        size_t addr = (size_t)b * DB + (c >> 4) * DTILE + n2 * 16 + (c & 15);
        *(float4*)(dryT + addr) = d;
        *(float4*)(KT + addr) = k;
    }
}

// ---- fwd col FFT: tile reads direct-to-reg, 2-round LDS transpose, tile write ----
__global__ void k_fwd(const float* __restrict__ dryT, const float* __restrict__ KT,
                      float2* __restrict__ C) {
    __shared__ float2 T[128 * TP];
    __shared__ float2 tw[256];
    __shared__ float2 fine[256];
    int t = threadIdx.x;
    int a = blockIdx.x >> 4;
    int cg = blockIdx.x & 15;
    {
        float sv, cv;
        __sincosf(-TWO_PI * (float)t * (1.0f / 256.0f), &sv, &cv);
        tw[t] = make_float2(cv, sv);
        __sincosf(-TWO_PI * (float)t * INV_L, &sv, &cv);
        fine[t] = make_float2(cv, sv);
    }
    int j = t >> 4, c = t & 15;
    int n1 = cg * 16 + c;
    const float* dT = dryT + (size_t)a * DB + cg * DTILE;
    const float* kT = KT + (size_t)a * DB + cg * DTILE;
    float2 r[16];
#pragma unroll
    for (int m = 0; m < 8; m++) {
        int n2 = j + 16 * m;                 // < 128
        r[m] = make_float2(dT[n2 * 16 + c], kT[n2 * 16 + c]);
    }
#pragma unroll
    for (int m = 8; m < 16; m++) r[m] = make_float2(0.f, 0.f);
    __syncthreads();                         // tables ready
#pragma unroll
    for (int m0 = 0; m0 < 4; m0++) bf4f(r[m0], r[m0 + 4], r[m0 + 8], r[m0 + 12], tw, 1, j + 16 * m0);
#pragma unroll
    for (int h = 0; h < 4; h++) bf4f(r[4 * h], r[4 * h + 1], r[4 * h + 2], r[4 * h + 3], tw, 4, j);
    // two-round transpose
    float2 r2[16];
#pragma unroll
    for (int m = 0; m < 8; m++) T[(j + 16 * m) * TP + c] = r[m];
    __syncthreads();
    if (j < 8) {
#pragma unroll
        for (int jj = 0; jj < 16; jj++) r2[jj] = T[(jj + 16 * j) * TP + c];
    }
    __syncthreads();
#pragma unroll
    for (int m = 8; m < 16; m++) T[(j + 16 * m - 128) * TP + c] = r[m];
    __syncthreads();
    if (j >= 8) {
#pragma unroll
        for (int jj = 0; jj < 16; jj++) r2[jj] = T[(jj + 16 * (j - 8)) * TP + c];
    }
#pragma unroll
    for (int q = 0; q < 4; q++) bf4f(r2[q], r2[q + 4], r2[q + 8], r2[q + 12], tw, 16, q);
#pragma unroll
    for (int h = 0; h < 4; h++) bf4f(r2[4 * h], r2[4 * h + 1], r2[4 * h + 2], r2[4 * h + 3], tw, 64, 0);
    float2* Ct = C + (size_t)a * CB + cg * TILE_C;
#pragma unroll
    for (int jj = 0; jj < 16; jj++) {
        int p = jj + 16 * j;
        int k2 = dr4(p);
        int ph = (n1 * k2) & (L - 1);
        float2 w = cmul(tw[ph >> 8], fine[ph & 255]);
        Ct[p * 16 + c] = cmul(r2[jj], w);
    }
}

// ---- pointwise unit: array0 at slot sJ/sN, array1 at +8; Y written in place (array0 rows) ----
__device__ __forceinline__ void pw_unit(float2* A, int sJ, int kJ, int sN, int kN) {
    float2 Z0j = A[sJ * ROWP + kJ],       Z0n = A[sN * ROWP + kN];
    float2 Z1j = A[(8 + sJ) * ROWP + kJ], Z1n = A[(8 + sN) * ROWP + kN];
    float2 D0 = make_float2(0.5f * (Z0j.x + Z0n.x), 0.5f * (Z0j.y - Z0n.y));
    float2 K0 = make_float2(0.5f * (Z0j.y + Z0n.y), 0.5f * (Z0n.x - Z0j.x));
    float2 D1 = make_float2(0.5f * (Z1j.x + Z1n.x), 0.5f * (Z1j.y - Z1n.y));
    float2 K1 = make_float2(0.5f * (Z1j.y + Z1n.y), 0.5f * (Z1n.x - Z1j.x));
    float2 W0 = cmul(D0, K0);
    float2 W1 = cmul(D1, K1);
    A[sJ * ROWP + kJ] = make_float2(W0.x - W1.y, W0.y + W1.x);
    A[sN * ROWP + kN] = make_float2(W0.x + W1.y, W1.x - W0.y);
}

// ---- fused row pass on 4-consecutive-position blocks (u, partner u') ----
// position p = p0 + 4u; freq of position p is dr4(p) = 64*p0 + w(u), w = 16p1+4p2+p3.
// partner freq: (A,o) <-> (B,3-o) since 256-(64o+w) = 64(3-o)+(64-w).
__global__ void k_rowpw(float2* __restrict__ C) {
    __shared__ float2 A[16 * ROWP];
    __shared__ float2 tw[192];
    int t = threadIdx.x;
    int pr = blockIdx.x / 33;
    int g = blockIdx.x % 33;
    int uA = 0, uB = 0;
    {
        int cnt = -1;
        for (int u = 0; u < 64; u++) {
            int w = 16 * (u & 3) + 4 * ((u >> 2) & 3) + (u >> 4);
            int wp = (64 - w) & 63;
            int up = (wp >> 4) + 4 * ((wp >> 2) & 3) + 16 * (wp & 3);
            if (u <= up) { cnt++; if (cnt == g) { uA = u; uB = up; break; } }
        }
    }
    bool self = (uA == uB);
    int nblk = self ? 1 : 2;
    if (t < 192) {
        float sv, cv;
        __sincosf(-TWO_PI * (float)t * (1.0f / 256.0f), &sv, &cv);
        tw[t] = make_float2(cv, sv);
    }
    float2* b0 = C + (size_t)(2 * pr) * CB;
    float2* b1 = b0 + CB;
    for (int arr = 0; arr < 2; arr++) {
        const float2* src = arr ? b1 : b0;
        for (int blk = 0; blk < nblk; blk++) {
            int u = blk ? uB : uA;
            int sb = arr * 8 + blk * 4;
            for (int idx = t; idx < 1024; idx += 256) {
                int cg = idx >> 6, rem = idx & 63;
                int o = rem >> 4;
                A[(sb + o) * ROWP + 16 * cg + (idx & 15)] = src[cg * TILE_C + 64 * u + rem];
            }
        }
    }
    __syncthreads();
    int NR = nblk * 8;
#pragma unroll
    for (int lm = 8; lm >= 6; lm -= 2) {
        int Q = 1 << (lm - 2), f = 256 >> lm;
        for (int v = t; v < NR * 64; v += 256) {
            int ri = v >> 6, qi = v & 63;
            int slot = self ? ((ri >> 2) * 8 + (ri & 3)) : ri;
            int q = qi & (Q - 1);
            int i0 = ((qi - q) << 2) + q;
            bfly4_fwd(A, slot * ROWP + i0, Q, tw, f, q);
        }
        __syncthreads();
    }
#pragma unroll
    for (int lm = 4; lm >= 2; lm -= 2) {
        int Q = 1 << (lm - 2), f = 256 >> lm;
        for (int v = t; v < NR * 64; v += 256) {
            int ri = self ? (v & 7) : (v & 15);
            int qi = self ? (v >> 3) : (v >> 4);
            int slot = self ? ((ri >> 2) * 8 + (ri & 3)) : ri;
            int q = qi & (Q - 1);
            int i0 = ((qi - q) << 2) + q;
            bfly4_fwd(A, slot * ROWP + i0, Q, tw, f, q);
        }
        __syncthreads();
    }
    // pointwise (within-row spectrum in dr4-position order; partner col = 255-t, freq0 row dr4-based)
    if (!self) {
        pw_unit(A, 0, t, 7, 255 - t);
        pw_unit(A, 1, t, 6, 255 - t);
        pw_unit(A, 2, t, 5, 255 - t);
        pw_unit(A, 3, t, 4, 255 - t);
    } else if (uA == 0) {          // freqs {0,64,128,192}
        pw_unit(A, 1, t, 3, 255 - t);
        if (t < 128) pw_unit(A, 2, t, 2, 255 - t);
        if (t == 0) { pw_unit(A, 0, 0, 0, 0); pw_unit(A, 0, 2, 0, 2); }
        else if (t < 128) pw_unit(A, 0, dr4(t), 0, dr4(256 - t));
    } else {                       // uA == 2: freqs {32,96,160,224}
        pw_unit(A, 0, t, 3, 255 - t);
        pw_unit(A, 1, t, 2, 255 - t);
    }
    __syncthreads();
    int NRI = nblk * 4;
#pragma unroll
    for (int lm = 2; lm <= 4; lm += 2) {
        int Q = 1 << (lm - 2), f = 256 >> lm;
        for (int v = t; v < NRI * 64; v += 256) {
            int ri = self ? (v & 3) : (v & 7);
            int qi = self ? (v >> 2) : (v >> 3);
            int q = qi & (Q - 1);
            int i0 = ((qi - q) << 2) + q;
            bfly4_inv(A, ri * ROWP + i0, Q, tw, f, q);
        }
        __syncthreads();
    }
#pragma unroll
    for (int lm = 6; lm <= 8; lm += 2) {
        int Q = 1 << (lm - 2), f = 256 >> lm;
        for (int v = t; v < NRI * 64; v += 256) {
            int ri = v >> 6, qi = v & 63;
            int q = qi & (Q - 1);
            int i0 = ((qi - q) << 2) + q;
            bfly4_inv(A, ri * ROWP + i0, Q, tw, f, q);
        }
        __syncthreads();
    }
    // inverse big twiddle (true freq k2 = 64*o + w) + tile store into b0
    for (int blk = 0; blk < nblk; blk++) {
        int u = blk ? uB : uA;
        int w = 16 * (u & 3) + 4 * ((u >> 2) & 3) + (u >> 4);
        for (int idx = t; idx < 1024; idx += 256) {
            int cg = idx >> 6, rem = idx & 63;
            int o = rem >> 4;
            int f = 16 * cg + (idx & 15);
            int k2 = 64 * o + w;
            float2 v = A[(blk * 4 + o) * ROWP + f];
            int ph = (f * k2) & (L - 1);
            float sv, cv;
            __sincosf(TWO_PI * (float)ph * INV_L, &sv, &cv);
            b0[cg * TILE_C + 64 * u + rem] = cmul(v, make_float2(cv, sv));
        }
    }
}

// ---- inverse col pass: tile reads, 2-round transpose, mix + partial max, tiled wout ----
__global__ void k_colinv(const float2* __restrict__ C, const float* __restrict__ dryT,
                         const float* __restrict__ mixv, float* __restrict__ wout,
                         float* __restrict__ partial) {
    __shared__ float2 T[128 * TP];
    __shared__ float2 tw[256];
    __shared__ float sm0[4], sm1[4];
    int t = threadIdx.x;
    int a = blockIdx.x >> 4;       // pair
    int cg = blockIdx.x & 15;
    {
        float sv, cv;
        __sincosf(-TWO_PI * (float)t * (1.0f / 256.0f), &sv, &cv);
        tw[t] = make_float2(cv, sv);
    }
    int j = t >> 4, c = t & 15;
    const float2* Ct = C + (size_t)(2 * a) * CB + cg * TILE_C;
    float2 r[16];
#pragma unroll
    for (int jj = 0; jj < 16; jj++) r[jj] = Ct[(jj + 16 * j) * 16 + c];
    __syncthreads();
#pragma unroll
    for (int h = 0; h < 4; h++) bf4i(r[4 * h], r[4 * h + 1], r[4 * h + 2], r[4 * h + 3], tw, 64, 0);
#pragma unroll
    for (int q = 0; q < 4; q++) bf4i(r[q], r[q + 4], r[q + 8], r[q + 12], tw, 16, q);
    float2 r2[16];
    if (j < 8) {
#pragma unroll
        for (int jj = 0; jj < 16; jj++) T[(jj + 16 * j) * TP + c] = r[jj];
    }
    __syncthreads();
#pragma unroll
    for (int m = 0; m < 8; m++) r2[m] = T[(j + 16 * m) * TP + c];
    __syncthreads();
    if (j >= 8) {
#pragma unroll
        for (int jj = 0; jj < 16; jj++) T[(16 * (j - 8) + jj) * TP + c] = r[jj];
    }
    __syncthreads();
#pragma unroll
    for (int m = 8; m < 16; m++) r2[m] = T[(j + 16 * (m - 8)) * TP + c];
#pragma unroll
    for (int h = 0; h < 4; h++) bf4i(r2[4 * h], r2[4 * h + 1], r2[4 * h + 2], r2[4 * h + 3], tw, 4, j);
#pragma unroll
    for (int m0 = 0; m0 < 4; m0++) bf4i(r2[m0], r2[m0 + 4], r2[m0 + 8], r2[m0 + 12], tw, 1, j + 16 * m0);
    int b0 = 2 * a, b1 = 2 * a + 1;
    float mix0 = mixv[b0], mix1 = mixv[b1];
    float om0 = 1.f - mix0, om1 = 1.f - mix1;
    const float* d0T = dryT + (size_t)b0 * DB + cg * DTILE;
    const float* d1T = dryT + (size_t)b1 * DB + cg * DTILE;
    float* w0T = wout + (size_t)b0 * DB + cg * DTILE;
    float* w1T = wout + (size_t)b1 * DB + cg * DTILE;
    float m0 = -3.4e38f, m1 = -3.4e38f;
#pragma unroll
    for (int m = 0; m < 8; m++) {
        int n2 = j + 16 * m;               // < 128
        int o = n2 * 16 + c;
        float d0 = d0T[o], d1 = d1T[o];
        float o0 = mix0 * (r2[m].x * INV_L) + om0 * d0;
        float o1 = mix1 * (r2[m].y * INV_L) + om1 * d1;
        w0T[o] = o0;
        w1T[o] = o1;
        m0 = fmaxf(m0, o0);
        m1 = fmaxf(m1, o1);
    }
#pragma unroll
    for (int off = 32; off > 0; off >>= 1) {
        m0 = fmaxf(m0, __shfl_down(m0, off));
        m1 = fmaxf(m1, __shfl_down(m1, off));
    }
    if ((t & 63) == 0) { sm0[t >> 6] = m0; sm1[t >> 6] = m1; }
    __syncthreads();
    if (t == 0) {
        partial[b0 * 16 + cg] = fmaxf(fmaxf(sm0[0], sm0[1]), fmaxf(sm0[2], sm0[3]));
        partial[b1 * 16 + cg] = fmaxf(fmaxf(sm1[0], sm1[1]), fmaxf(sm1[2], sm1[3]));
    }
}

// ---- normalize: tiled wout -> LDS transpose -> linear out (coalesced) ----
__global__ void k_norm(const float* __restrict__ wout, const float* __restrict__ partial,
                       float* __restrict__ out) {
    __shared__ float buf[32 * 260];
    __shared__ float smx_s;
    int t = threadIdx.x;
    int b = blockIdx.x >> 2;
    int grp = blockIdx.x & 3;       // n2 range [32*grp, +32)
    if (t < 16) {
        float p = partial[b * 16 + t];
#pragma unroll
        for (int off = 8; off > 0; off >>= 1) p = fmaxf(p, __shfl_down(p, off, 16));
        if (t == 0) smx_s = p;
    }
    __syncthreads();
    float inv = 1.f / (smx_s + 1e-8f);
    const float* wb = wout + (size_t)b * DB;
#pragma unroll
    for (int i = 0; i < 8; i++) {
        int f = i * 1024 + t * 4;        // (cg, n2r, cc)
        int cg = f >> 9, rem = f & 511;
        int n2r = rem >> 4, cc = rem & 15;
        float4 v = *(const float4*)(wb + cg * DTILE + (32 * grp + n2r) * 16 + cc);
        *(float4*)&buf[n2r * 260 + 16 * cg + cc] = v;
    }
    __syncthreads();
    float* ob = out + (size_t)b * N_T + grp * 8192;
#pragma unroll
    for (int i = 0; i < 8; i++) {
        int f = i * 1024 + t * 4;        // n2r-major linear
        int n2r = f >> 8, n1 = f & 255;
        float4 v = *(float4*)&buf[n2r * 260 + n1];
        v.x *= inv; v.y *= inv; v.z *= inv; v.w *= inv;
        *(float4*)(ob + f) = v;
    }
}

extern "C" void kernel_launch(void* const* d_in, const int* in_sizes, int n_in,
                              void* d_out, int out_size, void* d_ws, size_t ws_size,
                              hipStream_t stream) {
    const float* events = (const float*)d_in[0];
    const int* indices = (const int*)d_in[1];
    const float* g      = (const float*)d_in[2];
    const float* rooms  = (const float*)d_in[3];
    const float* w_room = (const float*)d_in[4];
    const float* b_room = (const float*)d_in[5];
    const float* w_mix  = (const float*)d_in[6];
    const float* b_mix  = (const float*)d_in[7];
    float* out = (float*)d_out;

    char* ws = (char*)d_ws;
    float2* C = (float2*)ws;                       // [64][16 tiles][256][16] float2 = 32 MB
    size_t off = (size_t)BATCH * CB * sizeof(float2);
    float* dryT = (float*)(ws + off);              // [64][16][128][16] = 8 MB
    off += (size_t)BATCH * DB * sizeof(float);
    float* KT = (float*)(ws + off);                // 8 MB
    off += (size_t)BATCH * DB * sizeof(float);
    float* wout = (float*)(ws + off);              // 8 MB
    off += (size_t)BATCH * DB * sizeof(float);
    float* wroom = (float*)(ws + off);
    off += BATCH * NROOM * sizeof(float);
    float* mixv = (float*)(ws + off);
    off += BATCH * sizeof(float);
    float* partial = (float*)(ws + off);

    k_prep<<<1, 64, 0, stream>>>(g, w_room, b_room, w_mix, b_mix, wroom, mixv);
    k_dryk<<<BATCH * 8, 256, 0, stream>>>(events, indices, rooms, wroom, dryT, KT);
    k_fwd<<<BATCH * 16, 256, 0, stream>>>(dryT, KT, C);
    k_rowpw<<<NPAIR * 33, 256, 0, stream>>>(C);
    k_colinv<<<NPAIR * 16, 256, 0, stream>>>(C, dryT, mixv, wout, partial);
    k_norm<<<BATCH * 4, 256, 0, stream>>>(wout, partial, out);
}